// Round 2
// baseline (866.425 us; speedup 1.0000x reference)
//
#include <hip/hip_runtime.h>
#include <hip/hip_bf16.h>
#include <stdint.h>

#define FLEN 4096
#define TLEN 512
#define NB   4
#define NH   8

typedef __attribute__((ext_vector_type(8))) short short8;
typedef __attribute__((ext_vector_type(4))) float floatx4;

__device__ inline unsigned short f2bf(float f) {
    union { float f; unsigned u; } v; v.f = f;
    unsigned r = (v.u + 0x7FFFu + ((v.u >> 16) & 1u)) >> 16;
    return (unsigned short)r;
}

__device__ inline short8 pack_bf16(floatx4 a, floatx4 b) {
    short8 r;
    r[0]=(short)f2bf(a[0]); r[1]=(short)f2bf(a[1]); r[2]=(short)f2bf(a[2]); r[3]=(short)f2bf(a[3]);
    r[4]=(short)f2bf(b[0]); r[5]=(short)f2bf(b[1]); r[6]=(short)f2bf(b[2]); r[7]=(short)f2bf(b[3]);
    return r;
}

// ---- transpose a 512x512 fp32 matrix into bf16 [out][in] ----
__global__ __launch_bounds__(256) void transpose_bf16(const float* __restrict__ src,
                                                      unsigned short* __restrict__ dst) {
    __shared__ float tile[64][65];
    int bx = blockIdx.x & 7, by = blockIdx.x >> 3;
    int rb = by * 64, cb = bx * 64;
    int tr = threadIdx.x >> 6;      // 0..3
    int tc = threadIdx.x & 63;      // 0..63
    #pragma unroll
    for (int i = 0; i < 16; ++i) {
        int rr = tr + i * 4;
        tile[rr][tc] = src[(size_t)(rb + rr) * 512 + cb + tc];
    }
    __syncthreads();
    #pragma unroll
    for (int i = 0; i < 16; ++i) {
        int rr = tr + i * 4;
        dst[(size_t)(cb + rr) * 512 + rb + tc] = f2bf(tile[tc][rr]);
    }
}

__global__ void combine_bias(const float* bq, const float* bfp, const float* bk, const float* btp,
                             float* bqf, float* bkt) {
    int i = blockIdx.x * blockDim.x + threadIdx.x;
    if (i < 512) { bqf[i] = bq[i] + bfp[i]; bkt[i] = bk[i] + btp[i]; }
}

// ---- generic [M,512]x[512,512] bf16-MFMA GEMM, fp32 A, bf16 W^T ----
// epi 0: Cf = acc + bias[c]
// epi 1: Cb(bf16) = acc + addsrc[(r%addmod)][c]
// epi 2: Vt layout: Cb[((b*8+h)*64+d)*512 + t] = acc + bias[c]
// epi 3: Cf = (f2 - mu)*rstd * (acc + bias[c] + 1)
__global__ __launch_bounds__(256) void gemm512(
    const float* __restrict__ A, const unsigned short* __restrict__ WT,
    const float* __restrict__ bias, const float* __restrict__ addsrc, int addmod,
    float* __restrict__ Cf, unsigned short* __restrict__ Cb,
    const float* __restrict__ f2, const float* __restrict__ stats, int epi)
{
    int tid = threadIdx.x;
    int w = tid >> 6, l = tid & 63;
    int fr = l & 15, g = l >> 4;
    int rb = blockIdx.x * 64 + w * 16;
    int cb = blockIdx.y * 64;

    floatx4 acc[4];
    #pragma unroll
    for (int ct = 0; ct < 4; ++ct)
        #pragma unroll
        for (int i = 0; i < 4; ++i) acc[ct][i] = 0.f;

    const float* ap = A + (size_t)(rb + fr) * 512;
    for (int ks = 0; ks < 16; ++ks) {
        floatx4 a0 = *(const floatx4*)(ap + ks * 32 + g * 8);
        floatx4 a1 = *(const floatx4*)(ap + ks * 32 + g * 8 + 4);
        short8 af = pack_bf16(a0, a1);
        #pragma unroll
        for (int ct = 0; ct < 4; ++ct) {
            short8 bf = *(const short8*)(WT + (size_t)(cb + ct * 16 + fr) * 512 + ks * 32 + g * 8);
            acc[ct] = __builtin_amdgcn_mfma_f32_16x16x32_bf16(af, bf, acc[ct], 0, 0, 0);
        }
    }

    #pragma unroll
    for (int ct = 0; ct < 4; ++ct) {
        #pragma unroll
        for (int i = 0; i < 4; ++i) {
            int r = rb + g * 4 + i;
            int c = cb + ct * 16 + fr;
            float v = acc[ct][i];
            if (epi == 0) {
                Cf[(size_t)r * 512 + c] = v + bias[c];
            } else if (epi == 1) {
                Cb[(size_t)r * 512 + c] = f2bf(v + addsrc[(size_t)(r % addmod) * 512 + c]);
            } else if (epi == 2) {
                int bb = r >> 9, t = r & 511, hh = c >> 6, d = c & 63;
                Cb[((size_t)((bb * 8 + hh) * 64 + d)) * 512 + t] = f2bf(v + bias[c]);
            } else {
                float mu = stats[r * 2], rs = stats[r * 2 + 1];
                Cf[(size_t)r * 512 + c] = (f2[(size_t)r * 512 + c] - mu) * rs * (v + bias[c] + 1.0f);
            }
        }
    }
}

// ---- gate: sigmoid(X@Wg + P@Wgp + bg + bgp + addb) -> G[rows][8] ----
__global__ __launch_bounds__(256) void gate_kernel(
    const float* __restrict__ X, const float* __restrict__ P,
    const float* __restrict__ Wg, const float* __restrict__ Wgp,
    const float* __restrict__ bg, const float* __restrict__ bgp,
    float addb, float* __restrict__ G, int posmod)
{
    int w = threadIdx.x >> 6, l = threadIdx.x & 63;
    int row = blockIdx.x * 4 + w;
    float a[8];
    #pragma unroll
    for (int j = 0; j < 8; ++j) a[j] = 0.f;
    const float* xr = X + (size_t)row * 512;
    const float* pr = P + (size_t)(row % posmod) * 512;
    for (int c = l; c < 512; c += 64) {
        float x = xr[c], p = pr[c];
        floatx4 w0 = *(const floatx4*)(Wg + c * 8);
        floatx4 w1 = *(const floatx4*)(Wg + c * 8 + 4);
        floatx4 p0 = *(const floatx4*)(Wgp + c * 8);
        floatx4 p1 = *(const floatx4*)(Wgp + c * 8 + 4);
        #pragma unroll
        for (int j = 0; j < 4; ++j) { a[j] += x * w0[j] + p * p0[j]; a[4 + j] += x * w1[j] + p * p1[j]; }
    }
    #pragma unroll
    for (int off = 1; off < 64; off <<= 1)
        #pragma unroll
        for (int j = 0; j < 8; ++j) a[j] += __shfl_xor(a[j], off);
    if (l == 0) {
        #pragma unroll
        for (int j = 0; j < 8; ++j) {
            float z = a[j] + bg[j] + bgp[j] + addb;
            G[(size_t)row * 8 + j] = 1.f / (1.f + __expf(-z));
        }
    }
}

// ---- per-row layernorm stats (mean, rstd) ----
__global__ __launch_bounds__(256) void ln_stats(const float* __restrict__ X, float* __restrict__ S) {
    int w = threadIdx.x >> 6, l = threadIdx.x & 63;
    int row = blockIdx.x * 4 + w;
    const floatx4* xr = (const floatx4*)(X + (size_t)row * 512);
    float s = 0.f, q = 0.f;
    #pragma unroll
    for (int i = 0; i < 2; ++i) {
        floatx4 v = xr[l * 2 + i];
        #pragma unroll
        for (int j = 0; j < 4; ++j) { s += v[j]; q += v[j] * v[j]; }
    }
    for (int off = 1; off < 64; off <<= 1) { s += __shfl_xor(s, off); q += __shfl_xor(q, off); }
    if (l == 0) {
        float mu = s * (1.f / 512.f);
        float var = q * (1.f / 512.f) - mu * mu;
        S[row * 2] = mu;
        S[row * 2 + 1] = rsqrtf(var + 1e-5f);
    }
}

// ---- fused attention: scores -> softmax -> gates -> probs(out) -> PV -> control ----
__global__ __launch_bounds__(256) void attn_kernel(
    const unsigned short* __restrict__ Q, const unsigned short* __restrict__ K,
    const unsigned short* __restrict__ Vt,
    const float* __restrict__ g_from, const float* __restrict__ g_to,
    float* __restrict__ probs, float* __restrict__ control)
{
    __shared__ unsigned short plds[4][8192];   // per-wave [16][512] bf16, XOR-swizzled
    int tid = threadIdx.x;
    int w = tid >> 6, l = tid & 63;
    int fr = l & 15, g = l >> 4;
    int bh = blockIdx.y, b = bh >> 3, h = bh & 7;
    int fb = blockIdx.x * 64 + w * 16;

    const unsigned short* qp = Q + (size_t)(b * FLEN + fb + fr) * 512 + h * 64 + g * 8;
    short8 qf0 = *(const short8*)qp;
    short8 qf1 = *(const short8*)(qp + 32);

    floatx4 sc[32];
    #pragma unroll
    for (int tt = 0; tt < 32; ++tt)
        #pragma unroll
        for (int i = 0; i < 4; ++i) sc[tt][i] = 0.f;

    #pragma unroll
    for (int tt = 0; tt < 32; ++tt) {
        const unsigned short* kp = K + (size_t)(b * TLEN + tt * 16 + fr) * 512 + h * 64 + g * 8;
        short8 kf0 = *(const short8*)kp;
        short8 kf1 = *(const short8*)(kp + 32);
        sc[tt] = __builtin_amdgcn_mfma_f32_16x16x32_bf16(qf0, kf0, sc[tt], 0, 0, 0);
        sc[tt] = __builtin_amdgcn_mfma_f32_16x16x32_bf16(qf1, kf1, sc[tt], 0, 0, 0);
    }

    // softmax over t (512), rows are (g*4+i), col within tile = fr
    float m[4];
    #pragma unroll
    for (int i = 0; i < 4; ++i) m[i] = -1e30f;
    #pragma unroll
    for (int tt = 0; tt < 32; ++tt)
        #pragma unroll
        for (int i = 0; i < 4; ++i) {
            float v = sc[tt][i] * 0.125f;   // 1/sqrt(64)
            sc[tt][i] = v;
            m[i] = fmaxf(m[i], v);
        }
    #pragma unroll
    for (int off = 1; off < 16; off <<= 1)
        #pragma unroll
        for (int i = 0; i < 4; ++i) m[i] = fmaxf(m[i], __shfl_xor(m[i], off));

    float s[4] = {0.f, 0.f, 0.f, 0.f};
    #pragma unroll
    for (int tt = 0; tt < 32; ++tt)
        #pragma unroll
        for (int i = 0; i < 4; ++i) {
            float p = __expf(sc[tt][i] - m[i]);
            sc[tt][i] = p;
            s[i] += p;
        }
    #pragma unroll
    for (int off = 1; off < 16; off <<= 1)
        #pragma unroll
        for (int i = 0; i < 4; ++i) s[i] += __shfl_xor(s[i], off);

    float fac[4];
    #pragma unroll
    for (int i = 0; i < 4; ++i)
        fac[i] = g_from[(size_t)(b * FLEN + fb + g * 4 + i) * 8 + h] / s[i];

    size_t prow = (size_t)(bh * FLEN + fb) * 512;
    #pragma unroll
    for (int tt = 0; tt < 32; ++tt) {
        int t = tt * 16 + fr;
        float gt = g_to[(size_t)(b * TLEN + t) * 8 + h];
        #pragma unroll
        for (int i = 0; i < 4; ++i) {
            int row = g * 4 + i;
            float p = sc[tt][i] * fac[i] * gt;
            probs[prow + (size_t)row * 512 + t] = p;
            plds[w][(row * 512 + t) ^ ((row & 7) << 3)] = f2bf(p);
        }
    }

    floatx4 oacc[4];
    #pragma unroll
    for (int dt = 0; dt < 4; ++dt)
        #pragma unroll
        for (int i = 0; i < 4; ++i) oacc[dt][i] = 0.f;

    #pragma unroll
    for (int ks = 0; ks < 16; ++ks) {
        short8 pf = *(const short8*)&plds[w][(fr * 512 + ks * 32 + g * 8) ^ ((fr & 7) << 3)];
        #pragma unroll
        for (int dt = 0; dt < 4; ++dt) {
            const unsigned short* vp = Vt + (size_t)(bh * 64 + dt * 16 + fr) * 512 + ks * 32 + g * 8;
            short8 vf = *(const short8*)vp;
            oacc[dt] = __builtin_amdgcn_mfma_f32_16x16x32_bf16(pf, vf, oacc[dt], 0, 0, 0);
        }
    }

    #pragma unroll
    for (int dt = 0; dt < 4; ++dt)
        #pragma unroll
        for (int i = 0; i < 4; ++i)
            control[(size_t)(b * FLEN + fb + g * 4 + i) * 512 + h * 64 + dt * 16 + fr] = oacc[dt][i];
}

extern "C" void kernel_launch(void* const* d_in, const int* in_sizes, int n_in,
                              void* d_out, int out_size, void* d_ws, size_t ws_size,
                              hipStream_t stream) {
    const float* from = (const float*)d_in[0];
    const float* to   = (const float*)d_in[1];
    const float* fpos = (const float*)d_in[2];
    const float* tpos = (const float*)d_in[3];
    const float* Wq  = (const float*)d_in[4];  const float* bq  = (const float*)d_in[5];
    const float* Wk  = (const float*)d_in[6];  const float* bk  = (const float*)d_in[7];
    const float* Wv  = (const float*)d_in[8];  const float* bv  = (const float*)d_in[9];
    const float* Wfp = (const float*)d_in[10]; const float* bfp = (const float*)d_in[11];
    const float* Wtp = (const float*)d_in[12]; const float* btp = (const float*)d_in[13];
    const float* Wg_to   = (const float*)d_in[14]; const float* bg_to   = (const float*)d_in[15];
    const float* Wgp_to  = (const float*)d_in[16]; const float* bgp_to  = (const float*)d_in[17];
    const float* Wg_from = (const float*)d_in[18]; const float* bg_from = (const float*)d_in[19];
    const float* Wgp_from= (const float*)d_in[20]; const float* bgp_from= (const float*)d_in[21];
    const float* Wm  = (const float*)d_in[22]; const float* bm  = (const float*)d_in[23];

    char* ws = (char*)d_ws;
    unsigned short* WqT  = (unsigned short*)ws; ws += 512 * 512 * 2;
    unsigned short* WkT  = (unsigned short*)ws; ws += 512 * 512 * 2;
    unsigned short* WvT  = (unsigned short*)ws; ws += 512 * 512 * 2;
    unsigned short* WfpT = (unsigned short*)ws; ws += 512 * 512 * 2;
    unsigned short* WtpT = (unsigned short*)ws; ws += 512 * 512 * 2;
    unsigned short* WmT  = (unsigned short*)ws; ws += 512 * 512 * 2;
    float* bqf  = (float*)ws; ws += 512 * 4;
    float* bkt  = (float*)ws; ws += 512 * 4;
    float* posQ = (float*)ws; ws += (size_t)FLEN * 512 * 4;
    float* posK = (float*)ws; ws += (size_t)TLEN * 512 * 4;
    unsigned short* Qbf = (unsigned short*)ws; ws += (size_t)NB * FLEN * 512 * 2;
    unsigned short* Kbf = (unsigned short*)ws; ws += (size_t)NB * TLEN * 512 * 2;
    unsigned short* Vt  = (unsigned short*)ws; ws += (size_t)NB * NH * 64 * 512 * 2;
    float* gFrom = (float*)ws; ws += (size_t)NB * FLEN * 8 * 4;
    float* gTo   = (float*)ws; ws += (size_t)NB * TLEN * 8 * 4;
    float* control = (float*)ws; ws += (size_t)NB * FLEN * 512 * 4;
    float* stats = (float*)ws; ws += (size_t)NB * FLEN * 2 * 4;
    if (ws_size < (size_t)(ws - (char*)d_ws)) return;  // insufficient workspace -> visible failure

    // weight prep
    transpose_bf16<<<64, 256, 0, stream>>>(Wq,  WqT);
    transpose_bf16<<<64, 256, 0, stream>>>(Wk,  WkT);
    transpose_bf16<<<64, 256, 0, stream>>>(Wv,  WvT);
    transpose_bf16<<<64, 256, 0, stream>>>(Wfp, WfpT);
    transpose_bf16<<<64, 256, 0, stream>>>(Wtp, WtpT);
    transpose_bf16<<<64, 256, 0, stream>>>(Wm,  WmT);
    combine_bias<<<2, 256, 0, stream>>>(bq, bfp, bk, btp, bqf, bkt);

    // position projections (shared across batch)
    gemm512<<<dim3(FLEN / 64, 8), 256, 0, stream>>>(fpos, WfpT, bqf, nullptr, 1, posQ, nullptr, nullptr, nullptr, 0);
    gemm512<<<dim3(TLEN / 64, 8), 256, 0, stream>>>(tpos, WtpT, bkt, nullptr, 1, posK, nullptr, nullptr, nullptr, 0);

    // Q/K/V projections
    gemm512<<<dim3(NB * FLEN / 64, 8), 256, 0, stream>>>(from, WqT, nullptr, posQ, FLEN, nullptr, Qbf, nullptr, nullptr, 1);
    gemm512<<<dim3(NB * TLEN / 64, 8), 256, 0, stream>>>(to, WkT, nullptr, posK, TLEN, nullptr, Kbf, nullptr, nullptr, 1);
    gemm512<<<dim3(NB * TLEN / 64, 8), 256, 0, stream>>>(to, WvT, bv, nullptr, 1, nullptr, Vt, nullptr, nullptr, 2);

    // gates + layernorm stats
    gate_kernel<<<NB * FLEN / 4, 256, 0, stream>>>(from, fpos, Wg_from, Wgp_from, bg_from, bgp_from, 1.0f, gFrom, FLEN);
    gate_kernel<<<NB * TLEN / 4, 256, 0, stream>>>(to, tpos, Wg_to, Wgp_to, bg_to, bgp_to, 0.0f, gTo, TLEN);
    ln_stats<<<NB * FLEN / 4, 256, 0, stream>>>(from, stats);

    // attention (writes probs into d_out tail + control into ws)
    float* out = (float*)d_out;
    attn_kernel<<<dim3(FLEN / 64, NB * NH), 256, 0, stream>>>(Qbf, Kbf, Vt, gFrom, gTo,
                                                              out + (size_t)NB * FLEN * 512, control);

    // modulation + layernorm epilogue
    gemm512<<<dim3(NB * FLEN / 64, 8), 256, 0, stream>>>(control, WmT, bm, nullptr, 1, out, nullptr, from, stats, 3);
}

// Round 3
// 800.158 us; speedup vs baseline: 1.0828x; 1.0828x over previous
//
#include <hip/hip_runtime.h>
#include <hip/hip_bf16.h>
#include <stdint.h>

#define FLEN 4096
#define TLEN 512
#define NB   4
#define NH   8

typedef __attribute__((ext_vector_type(8))) short short8;
typedef __attribute__((ext_vector_type(4))) float floatx4;
typedef unsigned short ushort_t;
typedef unsigned int uint_t;

typedef __attribute__((address_space(1))) const void gconst_as;
typedef __attribute__((address_space(3))) void lds_as;

__device__ inline ushort_t f2bf(float f) {
    union { float f; uint_t u; } v; v.f = f;
    uint_t r = (v.u + 0x7FFFu + ((v.u >> 16) & 1u)) >> 16;
    return (ushort_t)r;
}
__device__ inline float bf2f(uint_t u) {
    union { uint_t u; float f; } v; v.u = u << 16;
    return v.f;
}
__device__ inline short8 pack_bf16(floatx4 a, floatx4 b) {
    short8 r;
    r[0]=(short)f2bf(a[0]); r[1]=(short)f2bf(a[1]); r[2]=(short)f2bf(a[2]); r[3]=(short)f2bf(a[3]);
    r[4]=(short)f2bf(b[0]); r[5]=(short)f2bf(b[1]); r[6]=(short)f2bf(b[2]); r[7]=(short)f2bf(b[3]);
    return r;
}

// ---- fp32 -> bf16 conversion, fused per-row LN stats (for `from`) ----
__global__ __launch_bounds__(256) void conv_from_stats(const float* __restrict__ X,
                                                       ushort_t* __restrict__ Xb,
                                                       float* __restrict__ S) {
    int w = threadIdx.x >> 6, l = threadIdx.x & 63;
    int row = blockIdx.x * 4 + w;
    const float* xr = X + (size_t)row * 512;
    floatx4 v0 = *(const floatx4*)(xr + l * 8);
    floatx4 v1 = *(const floatx4*)(xr + l * 8 + 4);
    *(short8*)(Xb + (size_t)row * 512 + l * 8) = pack_bf16(v0, v1);
    float s = 0.f, q = 0.f;
    #pragma unroll
    for (int j = 0; j < 4; ++j) { s += v0[j] + v1[j]; q += v0[j]*v0[j] + v1[j]*v1[j]; }
    #pragma unroll
    for (int off = 1; off < 64; off <<= 1) { s += __shfl_xor(s, off); q += __shfl_xor(q, off); }
    if (l == 0) {
        float mu = s * (1.f / 512.f);
        float var = q * (1.f / 512.f) - mu * mu;
        S[row * 2] = mu;
        S[row * 2 + 1] = rsqrtf(var + 1e-5f);
    }
}

// ---- generic fp32 -> bf16 (n8 = elems/8) ----
__global__ void conv_bf16(const float* __restrict__ X, ushort_t* __restrict__ Y, int n8) {
    int i = blockIdx.x * blockDim.x + threadIdx.x;
    if (i < n8) {
        floatx4 v0 = *(const floatx4*)(X + (size_t)i * 8);
        floatx4 v1 = *(const floatx4*)(X + (size_t)i * 8 + 4);
        *(short8*)(Y + (size_t)i * 8) = pack_bf16(v0, v1);
    }
}

// ---- transpose 512x512 fp32 -> bf16 [out][in] ----
__global__ __launch_bounds__(256) void transpose_bf16(const float* __restrict__ src,
                                                      ushort_t* __restrict__ dst) {
    __shared__ float tile[64][65];
    int bx = blockIdx.x & 7, by = blockIdx.x >> 3;
    int rb = by * 64, cb = bx * 64;
    int tr = threadIdx.x >> 6, tc = threadIdx.x & 63;
    #pragma unroll
    for (int i = 0; i < 16; ++i) {
        int rr = tr + i * 4;
        tile[rr][tc] = src[(size_t)(rb + rr) * 512 + cb + tc];
    }
    __syncthreads();
    #pragma unroll
    for (int i = 0; i < 16; ++i) {
        int rr = tr + i * 4;
        dst[(size_t)(cb + rr) * 512 + rb + tc] = f2bf(tile[tc][rr]);
    }
}

__global__ void combine_bias(const float* bq, const float* bfp, const float* bk, const float* btp,
                             float* bqf, float* bkt) {
    int i = blockIdx.x * blockDim.x + threadIdx.x;
    if (i < 512) { bqf[i] = bq[i] + bfp[i]; bkt[i] = bk[i] + btp[i]; }
}

// ---- tiled bf16 GEMM: [M,512] x WT[512n][512k] -> 128x128 tile, BK=32, 4 waves ----
// epi 0: Cb = bf16(acc + bias[c])
// epi 1: Cb = bf16(acc + bf2f(addsrc[(r%addmod)*512+c]))
// epi 2: permuted-V layout (see attn PV sigma map)
// epi 3: Cf = (f2 - mu)*rstd * (acc + bias[c] + 1)
__global__ __launch_bounds__(256) void gemm_bf16(
    const ushort_t* __restrict__ A, const ushort_t* __restrict__ WT,
    const float* __restrict__ bias, const ushort_t* __restrict__ addsrc, int addmod,
    float* __restrict__ Cf, ushort_t* __restrict__ Cb,
    const float* __restrict__ f2, const float* __restrict__ stats, int epi)
{
    __shared__ ushort_t As[128 * 32];
    __shared__ ushort_t Bs[128 * 32];
    int tid = threadIdx.x;
    int w = tid >> 6, l = tid & 63, fr = l & 15, g = l >> 4;
    int wr = w >> 1, wc = w & 1;
    int rb = blockIdx.x * 128, cb = blockIdx.y * 128;

    floatx4 acc[4][4];
    #pragma unroll
    for (int mt = 0; mt < 4; ++mt)
        #pragma unroll
        for (int nt = 0; nt < 4; ++nt)
            #pragma unroll
            for (int i = 0; i < 4; ++i) acc[mt][nt][i] = 0.f;

    int srow = tid >> 2;           // 0..63
    int scol = (tid & 3) * 8;      // 0,8,16,24
    for (int kb = 0; kb < 512; kb += 32) {
        #pragma unroll
        for (int i = 0; i < 2; ++i) {
            const ushort_t* ga = A  + (size_t)(rb + i * 64 + srow) * 512 + kb + scol;
            const ushort_t* gb = WT + (size_t)(cb + i * 64 + srow) * 512 + kb + scol;
            __builtin_amdgcn_global_load_lds((gconst_as*)ga, (lds_as*)(As + i * 2048 + w * 512), 16, 0, 0);
            __builtin_amdgcn_global_load_lds((gconst_as*)gb, (lds_as*)(Bs + i * 2048 + w * 512), 16, 0, 0);
        }
        __syncthreads();
        short8 af[4], bf[4];
        #pragma unroll
        for (int mt = 0; mt < 4; ++mt)
            af[mt] = *(const short8*)&As[(wr * 64 + mt * 16 + fr) * 32 + g * 8];
        #pragma unroll
        for (int nt = 0; nt < 4; ++nt)
            bf[nt] = *(const short8*)&Bs[(wc * 64 + nt * 16 + fr) * 32 + g * 8];
        #pragma unroll
        for (int mt = 0; mt < 4; ++mt)
            #pragma unroll
            for (int nt = 0; nt < 4; ++nt)
                acc[mt][nt] = __builtin_amdgcn_mfma_f32_16x16x32_bf16(af[mt], bf[nt], acc[mt][nt], 0, 0, 0);
        __syncthreads();
    }

    #pragma unroll
    for (int mt = 0; mt < 4; ++mt) {
        #pragma unroll
        for (int nt = 0; nt < 4; ++nt) {
            #pragma unroll
            for (int i = 0; i < 4; ++i) {
                int r = rb + wr * 64 + mt * 16 + g * 4 + i;
                int c = cb + wc * 64 + nt * 16 + fr;
                float v = acc[mt][nt][i];
                if (epi == 0) {
                    Cb[(size_t)r * 512 + c] = f2bf(v + bias[c]);
                } else if (epi == 1) {
                    Cb[(size_t)r * 512 + c] = f2bf(v + bf2f(addsrc[(size_t)(r % addmod) * 512 + c]));
                } else if (epi == 2) {
                    int bb = r >> 9, t = r & 511, hh = c >> 6, d = c & 63;
                    size_t idx = ((size_t)((bb * 8 + hh) * 64 + d)) * 512 +
                                 (t & ~31) + ((t >> 2) & 3) * 8 + ((t >> 4) & 1) * 4 + (t & 3);
                    Cb[idx] = f2bf(v + bias[c]);
                } else {
                    float mu = stats[r * 2], rs = stats[r * 2 + 1];
                    Cf[(size_t)r * 512 + c] = (f2[(size_t)r * 512 + c] - mu) * rs * (v + bias[c] + 1.0f);
                }
            }
        }
    }
}

// ---- gate: sigmoid(X@Wg + P@Wgp + bg + bgp + addb) ----
// layout 0: G[row*8+j]   layout 1: G[((row>>9)*8+j)*512 + (row&511)]
__global__ __launch_bounds__(256) void gate_kernel(
    const float* __restrict__ X, const float* __restrict__ P,
    const float* __restrict__ Wg, const float* __restrict__ Wgp,
    const float* __restrict__ bg, const float* __restrict__ bgp,
    float addb, float* __restrict__ G, int posmod, int layout)
{
    int w = threadIdx.x >> 6, l = threadIdx.x & 63;
    int row = blockIdx.x * 4 + w;
    float a[8];
    #pragma unroll
    for (int j = 0; j < 8; ++j) a[j] = 0.f;
    const float* xr = X + (size_t)row * 512;
    const float* pr = P + (size_t)(row % posmod) * 512;
    for (int c = l; c < 512; c += 64) {
        float x = xr[c], p = pr[c];
        floatx4 w0 = *(const floatx4*)(Wg + c * 8);
        floatx4 w1 = *(const floatx4*)(Wg + c * 8 + 4);
        floatx4 p0 = *(const floatx4*)(Wgp + c * 8);
        floatx4 p1 = *(const floatx4*)(Wgp + c * 8 + 4);
        #pragma unroll
        for (int j = 0; j < 4; ++j) { a[j] += x * w0[j] + p * p0[j]; a[4 + j] += x * w1[j] + p * p1[j]; }
    }
    #pragma unroll
    for (int off = 1; off < 64; off <<= 1)
        #pragma unroll
        for (int j = 0; j < 8; ++j) a[j] += __shfl_xor(a[j], off);
    if (l == 0) {
        #pragma unroll
        for (int j = 0; j < 8; ++j) {
            float z = a[j] + bg[j] + bgp[j] + addb;
            float gv = 1.f / (1.f + __expf(-z));
            if (layout == 0) G[(size_t)row * 8 + j] = gv;
            else G[((size_t)((row >> 9) * 8 + j)) * 512 + (row & 511)] = gv;
        }
    }
}

// ---- fused attention, swapped-QK layout, P in registers ----
__global__ __launch_bounds__(256, 3) void attn_kernel(
    const ushort_t* __restrict__ Q, const ushort_t* __restrict__ K,
    const ushort_t* __restrict__ Vp,
    const float* __restrict__ g_from, const float* __restrict__ gToT,
    float* __restrict__ probs, ushort_t* __restrict__ ctrl)
{
    __shared__ ushort_t ctile[4][16][72];
    int tid = threadIdx.x, w = tid >> 6, l = tid & 63;
    int fr = l & 15, g = l >> 4;
    int bh = blockIdx.y, b = bh >> 3, h = bh & 7;
    int fb = blockIdx.x * 64 + w * 16;
    int f = fb + fr;

    const ushort_t* qp = Q + ((size_t)(b * FLEN) + f) * 512 + h * 64 + g * 8;
    short8 qf0 = *(const short8*)qp;
    short8 qf1 = *(const short8*)(qp + 32);

    uint_t pbx[32], pby[32];
    float ssum = 0.f;
    const float* gtp = gToT + (size_t)bh * 512;

    #pragma unroll
    for (int tt = 0; tt < 32; ++tt) {
        const ushort_t* kp = K + ((size_t)(b * TLEN) + tt * 16 + fr) * 512 + h * 64 + g * 8;
        short8 kf0 = *(const short8*)kp;
        short8 kf1 = *(const short8*)(kp + 32);
        floatx4 sc = {0.f, 0.f, 0.f, 0.f};
        sc = __builtin_amdgcn_mfma_f32_16x16x32_bf16(kf0, qf0, sc, 0, 0, 0);  // C[t][f]
        sc = __builtin_amdgcn_mfma_f32_16x16x32_bf16(kf1, qf1, sc, 0, 0, 0);
        floatx4 gt = *(const floatx4*)(gtp + tt * 16 + g * 4);
        float e0 = __expf(sc[0] * 0.125f), e1 = __expf(sc[1] * 0.125f);
        float e2 = __expf(sc[2] * 0.125f), e3 = __expf(sc[3] * 0.125f);
        ssum += e0 + e1 + e2 + e3;                       // softmax denom (pre-gate!)
        float p0 = e0 * gt[0], p1 = e1 * gt[1], p2 = e2 * gt[2], p3 = e3 * gt[3];
        pbx[tt] = (uint_t)f2bf(p0) | ((uint_t)f2bf(p1) << 16);
        pby[tt] = (uint_t)f2bf(p2) | ((uint_t)f2bf(p3) << 16);
    }
    ssum += __shfl_xor(ssum, 16);
    ssum += __shfl_xor(ssum, 32);
    float fac = g_from[((size_t)(b * FLEN) + f) * 8 + h] / ssum;

    // PV: control^T[d][f] = sum_t V^T[d][t] * P^T[t][f]
    floatx4 oacc[4];
    #pragma unroll
    for (int dt = 0; dt < 4; ++dt)
        #pragma unroll
        for (int i = 0; i < 4; ++i) oacc[dt][i] = 0.f;

    #pragma unroll
    for (int kt = 0; kt < 16; ++kt) {
        union { uint_t u[4]; short8 v; } bu;
        bu.u[0] = pbx[2 * kt];     bu.u[1] = pby[2 * kt];
        bu.u[2] = pbx[2 * kt + 1]; bu.u[3] = pby[2 * kt + 1];
        #pragma unroll
        for (int dt = 0; dt < 4; ++dt) {
            const ushort_t* vp = Vp + ((size_t)(bh * 64) + dt * 16 + fr) * 512 + kt * 32 + g * 8;
            short8 vf = *(const short8*)vp;
            oacc[dt] = __builtin_amdgcn_mfma_f32_16x16x32_bf16(vf, bu.v, oacc[dt], 0, 0, 0);
        }
    }

    // control^T -> LDS -> coalesced bf16 control rows
    #pragma unroll
    for (int dt = 0; dt < 4; ++dt)
        #pragma unroll
        for (int i = 0; i < 4; ++i)
            ctile[w][fr][dt * 16 + g * 4 + i] = f2bf(oacc[dt][i] * fac);

    // probs (fp32, normalized+gated): lane holds f=fr row, t = tt*16+g*4..+4
    size_t prow = ((size_t)bh * FLEN + f) * 512;
    #pragma unroll
    for (int tt = 0; tt < 32; ++tt) {
        floatx4 pv;
        pv[0] = bf2f(pbx[tt] & 0xffffu) * fac;
        pv[1] = bf2f(pbx[tt] >> 16) * fac;
        pv[2] = bf2f(pby[tt] & 0xffffu) * fac;
        pv[3] = bf2f(pby[tt] >> 16) * fac;
        *(floatx4*)(probs + prow + tt * 16 + g * 4) = pv;
    }

    int fl = l >> 2, dp = (l & 3) * 16;
    uint4 c0 = *(const uint4*)&ctile[w][fl][dp];
    uint4 c1 = *(const uint4*)&ctile[w][fl][dp + 8];
    ushort_t* cdst = ctrl + ((size_t)(b * FLEN) + fb + fl) * 512 + h * 64 + dp;
    *(uint4*)cdst = c0;
    *(uint4*)(cdst + 8) = c1;
}

extern "C" void kernel_launch(void* const* d_in, const int* in_sizes, int n_in,
                              void* d_out, int out_size, void* d_ws, size_t ws_size,
                              hipStream_t stream) {
    const float* from = (const float*)d_in[0];
    const float* to   = (const float*)d_in[1];
    const float* fpos = (const float*)d_in[2];
    const float* tpos = (const float*)d_in[3];
    const float* Wq  = (const float*)d_in[4];  const float* bq  = (const float*)d_in[5];
    const float* Wk  = (const float*)d_in[6];  const float* bk  = (const float*)d_in[7];
    const float* Wv  = (const float*)d_in[8];  const float* bv  = (const float*)d_in[9];
    const float* Wfp = (const float*)d_in[10]; const float* bfp = (const float*)d_in[11];
    const float* Wtp = (const float*)d_in[12]; const float* btp = (const float*)d_in[13];
    const float* Wg_to   = (const float*)d_in[14]; const float* bg_to   = (const float*)d_in[15];
    const float* Wgp_to  = (const float*)d_in[16]; const float* bgp_to  = (const float*)d_in[17];
    const float* Wg_from = (const float*)d_in[18]; const float* bg_from = (const float*)d_in[19];
    const float* Wgp_from= (const float*)d_in[20]; const float* bgp_from= (const float*)d_in[21];
    const float* Wm  = (const float*)d_in[22]; const float* bm  = (const float*)d_in[23];

    char* ws = (char*)d_ws;
    ushort_t* WqT  = (ushort_t*)ws; ws += 512 * 512 * 2;
    ushort_t* WkT  = (ushort_t*)ws; ws += 512 * 512 * 2;
    ushort_t* WvT  = (ushort_t*)ws; ws += 512 * 512 * 2;
    ushort_t* WfpT = (ushort_t*)ws; ws += 512 * 512 * 2;
    ushort_t* WtpT = (ushort_t*)ws; ws += 512 * 512 * 2;
    ushort_t* WmT  = (ushort_t*)ws; ws += 512 * 512 * 2;
    float* bqf  = (float*)ws; ws += 512 * 4;
    float* bkt  = (float*)ws; ws += 512 * 4;
    ushort_t* fbf    = (ushort_t*)ws; ws += (size_t)NB * FLEN * 512 * 2;
    ushort_t* tbf    = (ushort_t*)ws; ws += (size_t)NB * TLEN * 512 * 2;
    ushort_t* posQb  = (ushort_t*)ws; ws += (size_t)FLEN * 512 * 2;
    ushort_t* posKb  = (ushort_t*)ws; ws += (size_t)TLEN * 512 * 2;
    ushort_t* Qbf = (ushort_t*)ws; ws += (size_t)NB * FLEN * 512 * 2;
    ushort_t* Kbf = (ushort_t*)ws; ws += (size_t)NB * TLEN * 512 * 2;
    ushort_t* Vp  = (ushort_t*)ws; ws += (size_t)NB * NH * 64 * 512 * 2;
    float* gFrom = (float*)ws; ws += (size_t)NB * FLEN * 8 * 4;
    float* gToT  = (float*)ws; ws += (size_t)NB * NH * 512 * 4;
    ushort_t* ctrl = (ushort_t*)ws; ws += (size_t)NB * FLEN * 512 * 2;
    float* stats = (float*)ws; ws += (size_t)NB * FLEN * 2 * 4;
    if (ws_size < (size_t)(ws - (char*)d_ws)) return;
    // alias: pos bf16 staging lives in ctrl (ctrl written only by attn, long after pos GEMMs)
    ushort_t* fposbf = ctrl;                       // 4096*512
    ushort_t* tposbf = ctrl + (size_t)FLEN * 512;  // 512*512

    conv_from_stats<<<NB * FLEN / 4, 256, 0, stream>>>(from, fbf, stats);
    conv_bf16<<<(NB * TLEN * 512 / 8) / 256, 256, 0, stream>>>(to, tbf, NB * TLEN * 512 / 8);
    conv_bf16<<<(FLEN * 512 / 8) / 256, 256, 0, stream>>>(fpos, fposbf, FLEN * 512 / 8);
    conv_bf16<<<(TLEN * 512 / 8) / 256, 256, 0, stream>>>(tpos, tposbf, TLEN * 512 / 8);

    transpose_bf16<<<64, 256, 0, stream>>>(Wq,  WqT);
    transpose_bf16<<<64, 256, 0, stream>>>(Wk,  WkT);
    transpose_bf16<<<64, 256, 0, stream>>>(Wv,  WvT);
    transpose_bf16<<<64, 256, 0, stream>>>(Wfp, WfpT);
    transpose_bf16<<<64, 256, 0, stream>>>(Wtp, WtpT);
    transpose_bf16<<<64, 256, 0, stream>>>(Wm,  WmT);
    combine_bias<<<2, 256, 0, stream>>>(bq, bfp, bk, btp, bqf, bkt);

    // position projections -> bf16
    gemm_bf16<<<dim3(FLEN / 128, 4), 256, 0, stream>>>(fposbf, WfpT, bqf, nullptr, 1, nullptr, posQb, nullptr, nullptr, 0);
    gemm_bf16<<<dim3(TLEN / 128, 4), 256, 0, stream>>>(tposbf, WtpT, bkt, nullptr, 1, nullptr, posKb, nullptr, nullptr, 0);

    // Q/K/V projections
    gemm_bf16<<<dim3(NB * FLEN / 128, 4), 256, 0, stream>>>(fbf, WqT, nullptr, posQb, FLEN, nullptr, Qbf, nullptr, nullptr, 1);
    gemm_bf16<<<dim3(NB * TLEN / 128, 4), 256, 0, stream>>>(tbf, WkT, nullptr, posKb, TLEN, nullptr, Kbf, nullptr, nullptr, 1);
    gemm_bf16<<<dim3(NB * TLEN / 128, 4), 256, 0, stream>>>(tbf, WvT, bv, nullptr, 1, nullptr, Vp, nullptr, nullptr, 2);

    gate_kernel<<<NB * FLEN / 4, 256, 0, stream>>>(from, fpos, Wg_from, Wgp_from, bg_from, bgp_from, 1.0f, gFrom, FLEN, 0);
    gate_kernel<<<NB * TLEN / 4, 256, 0, stream>>>(to, tpos, Wg_to, Wgp_to, bg_to, bgp_to, 0.0f, gToT, TLEN, 1);

    float* out = (float*)d_out;
    attn_kernel<<<dim3(FLEN / 64, NB * NH), 256, 0, stream>>>(Qbf, Kbf, Vp, gFrom, gToT,
                                                              out + (size_t)NB * FLEN * 512, ctrl);

    gemm_bf16<<<dim3(NB * FLEN / 128, 4), 256, 0, stream>>>(ctrl, WmT, bm, nullptr, 1, out, nullptr, from, stats, 3);
}